// Round 3
// baseline (464.634 us; speedup 1.0000x reference)
//
#include <hip/hip_runtime.h>
#include <type_traits>

#define DIN 1024
#define DIMM 1024
#define NH 16
#define HD 64
#define SEQ 2048
#define BATCH 2
#define MTOT (BATCH*SEQ)   // 4096
#define LDT 40             // GEMM LDS leading dim (32 + 8 pad)
#define LDP 72             // attn P-tile leading dim (64 + 8 pad)
#define LDV 66             // transpose LDS leading dim
#define SCALE 0.125f       // 1/sqrt(64)

typedef __bf16 bf16;
typedef __bf16 bf16x8 __attribute__((ext_vector_type(8)));
typedef float f32x4 __attribute__((ext_vector_type(4)));

// Load 8 contiguous elements as bf16x8, converting from fp32 if needed.
template<typename T>
__device__ __forceinline__ bf16x8 ld8bf16(const T* __restrict__ p) {
  if constexpr (std::is_same<T, float>::value) {
    const f32x4* q = (const f32x4*)p;
    f32x4 a = q[0], b = q[1];
    bf16x8 r;
    r[0] = (bf16)a[0]; r[1] = (bf16)a[1]; r[2] = (bf16)a[2]; r[3] = (bf16)a[3];
    r[4] = (bf16)b[0]; r[5] = (bf16)b[1]; r[6] = (bf16)b[2]; r[7] = (bf16)b[3];
    return r;
  } else {
    return *(const bf16x8*)p;
  }
}

// ---------------- GEMM: C = A * W^T ---------------- (unchanged this round)
template<typename TA, typename TW, typename TC>
__device__ __forceinline__ void gemm_bt_body(const TA* __restrict__ A,
                                             const TW* __restrict__ W,
                                             TC* __restrict__ C,
                                             int M, int N, int K) {
  __shared__ bf16 As[64 * LDT];
  __shared__ bf16 Ws[64 * LDT];
  const int tid  = threadIdx.x;
  const int wave = tid >> 6;
  const int lane = tid & 63;
  const int mbase = blockIdx.y * 64;
  const int nbase = blockIdx.x * 64;
  const int lr = tid >> 2;
  const int lc = (tid & 3) * 8;
  const int frow = lane & 15;
  const int quad = lane >> 4;
  const int fk   = quad * 8;

  f32x4 acc[4] = {};

  for (int k0 = 0; k0 < K; k0 += 32) {
    *(bf16x8*)&As[lr * LDT + lc] = ld8bf16(&A[(size_t)(mbase + lr) * K + k0 + lc]);
    *(bf16x8*)&Ws[lr * LDT + lc] = ld8bf16(&W[(size_t)(nbase + lr) * K + k0 + lc]);
    __syncthreads();
    bf16x8 af = *(const bf16x8*)&As[(wave * 16 + frow) * LDT + fk];
#pragma unroll
    for (int nt = 0; nt < 4; ++nt) {
      bf16x8 bfr = *(const bf16x8*)&Ws[(nt * 16 + frow) * LDT + fk];
      acc[nt] = __builtin_amdgcn_mfma_f32_16x16x32_bf16(af, bfr, acc[nt], 0, 0, 0);
    }
    __syncthreads();
  }
  const int crow = mbase + wave * 16 + quad * 4;
  const int ccol = nbase + frow;
#pragma unroll
  for (int nt = 0; nt < 4; ++nt)
#pragma unroll
    for (int rr = 0; rr < 4; ++rr) {
      if constexpr (std::is_same<TC, float>::value)
        C[(size_t)(crow + rr) * N + ccol + nt * 16] = acc[nt][rr];
      else
        C[(size_t)(crow + rr) * N + ccol + nt * 16] = (bf16)acc[nt][rr];
    }
}

__global__ __launch_bounds__(256) void qkv_gemm(const float* __restrict__ x,
                                                const float* __restrict__ wq,
                                                const float* __restrict__ wk,
                                                const float* __restrict__ wv,
                                                bf16* __restrict__ q,
                                                bf16* __restrict__ k,
                                                bf16* __restrict__ v) {
  const float* W = (blockIdx.z == 0) ? wq : (blockIdx.z == 1) ? wk : wv;
  bf16* C        = (blockIdx.z == 0) ? q  : (blockIdx.z == 1) ? k  : v;
  gemm_bt_body<float, float, bf16>(x, W, C, MTOT, DIMM, DIN);
}

__global__ __launch_bounds__(256) void proj_gemm(const bf16* __restrict__ A,
                                                 const float* __restrict__ W,
                                                 float* __restrict__ C) {
  gemm_bt_body<bf16, float, float>(A, W, C, MTOT, DIMM, DIMM);
}

// ---------------- V transpose: V (b*S+s, h*64+d) -> Vt ((b*16+h)*64+d, s) ---
__global__ __launch_bounds__(256) void vtrans(const bf16* __restrict__ V,
                                              bf16* __restrict__ Vt) {
  __shared__ bf16 T[64 * LDV];   // [s_local][d]
  const int bh = blockIdx.x >> 5;       // 0..31
  const int st = blockIdx.x & 31;       // s-tile 0..31
  const int b  = bh >> 4;
  const int h  = bh & 15;
  const int t  = threadIdx.x;
  const int sr = t >> 3;                // 0..31
  const int dc = (t & 7) * 8;           // 0..56

  const bf16* src = V + ((size_t)(b * SEQ + st * 64)) * DIMM + h * HD;
#pragma unroll
  for (int half = 0; half < 2; ++half) {
    const int row = sr + half * 32;
    *(bf16x8*)&T[row * LDV + dc] = *(const bf16x8*)&src[(size_t)row * DIMM + dc];
  }
  __syncthreads();
  bf16* dst = Vt + (size_t)bh * 64 * SEQ + st * 64;
#pragma unroll
  for (int half = 0; half < 2; ++half) {
    const int d = sr + half * 32;
    bf16x8 o;
#pragma unroll
    for (int j = 0; j < 8; ++j)
      o[j] = T[(dc + j) * LDV + d];
    *(bf16x8*)&dst[(size_t)d * SEQ + dc] = o;
  }
}

// ---------------- Causal flash attention (64-wide k-tiles, V^T input) -------
// Q,K: (B*S, 1024) bf16; Vt: ((b*16+h)*64+d, s).
// Block = 4 waves; wave handles one 16-row Q tile of one (b,h).
__global__ __launch_bounds__(256) void attn(const bf16* __restrict__ Q,
                                            const bf16* __restrict__ K,
                                            const bf16* __restrict__ Vt,
                                            bf16* __restrict__ O) {
  __shared__ bf16 Plds[4][16 * LDP];  // per-wave 16x64 P tile
  const int wave = threadIdx.x >> 6;
  const int lane = threadIdx.x & 63;
  const int lrow = lane & 15;
  const int quad = lane >> 4;
  const int nq = SEQ / 64;
  const int bh = blockIdx.x / nq;
  const int qc = blockIdx.x - bh * nq;
  const int b  = bh >> 4;
  const int h  = bh & 15;
  const int qbase = qc * 64 + wave * 16;

  const bf16* Qh  = Q  + (size_t)(b * SEQ) * DIMM + h * HD;
  const bf16* Kh  = K  + (size_t)(b * SEQ) * DIMM + h * HD;
  const bf16* Vth = Vt + (size_t)bh * 64 * SEQ;

  bf16x8 qf0 = *(const bf16x8*)&Qh[(size_t)(qbase + lrow) * DIMM + quad * 8];
  bf16x8 qf1 = *(const bf16x8*)&Qh[(size_t)(qbase + lrow) * DIMM + 32 + quad * 8];

  float m_i[4], l_i[4];
  f32x4 o_acc[4] = {};
#pragma unroll
  for (int r = 0; r < 4; ++r) { m_i[r] = -1e30f; l_i[r] = 0.f; }

  const int kend = qbase + 16;                 // exclusive causal bound
  for (int kbase = 0; kbase < kend; kbase += 64) {
    // ---- S = Q K^T : four 16-col groups, contraction d=64 ----
    f32x4 s[4] = {};
#pragma unroll
    for (int g = 0; g < 4; ++g) {
      bf16x8 kf;
      kf = *(const bf16x8*)&Kh[(size_t)(kbase + g * 16 + lrow) * DIMM + quad * 8];
      s[g] = __builtin_amdgcn_mfma_f32_16x16x32_bf16(qf0, kf, s[g], 0, 0, 0);
      kf = *(const bf16x8*)&Kh[(size_t)(kbase + g * 16 + lrow) * DIMM + 32 + quad * 8];
      s[g] = __builtin_amdgcn_mfma_f32_16x16x32_bf16(qf1, kf, s[g], 0, 0, 0);
    }
    // ---- causal mask + online softmax (rows = quad*4+r, cols = g*16+lrow) --
    float al[4];
#pragma unroll
    for (int r = 0; r < 4; ++r) {
      const int qrow = qbase + quad * 4 + r;
#pragma unroll
      for (int g = 0; g < 4; ++g)
        s[g][r] = (kbase + g * 16 + lrow > qrow) ? -1e30f : s[g][r];
      float pm = fmaxf(fmaxf(s[0][r], s[1][r]), fmaxf(s[2][r], s[3][r]));
      pm = fmaxf(pm, __shfl_xor(pm, 1));
      pm = fmaxf(pm, __shfl_xor(pm, 2));
      pm = fmaxf(pm, __shfl_xor(pm, 4));
      pm = fmaxf(pm, __shfl_xor(pm, 8));
      const float mn = fmaxf(m_i[r], pm);
      al[r] = __expf((m_i[r] - mn) * SCALE);
      float sum = 0.f;
#pragma unroll
      for (int g = 0; g < 4; ++g) {
        const float p = __expf((s[g][r] - mn) * SCALE);
        Plds[wave][(quad * 4 + r) * LDP + g * 16 + lrow] = (bf16)p;
        sum += p;
      }
      sum += __shfl_xor(sum, 1);
      sum += __shfl_xor(sum, 2);
      sum += __shfl_xor(sum, 4);
      sum += __shfl_xor(sum, 8);
      l_i[r] = l_i[r] * al[r] + sum;
      m_i[r] = mn;
    }
    // ---- rescale O ----
#pragma unroll
    for (int dt = 0; dt < 4; ++dt)
#pragma unroll
      for (int r = 0; r < 4; ++r)
        o_acc[dt][r] *= al[r];
    // ---- P: C-layout -> A-layout via per-wave LDS round trip ----
    asm volatile("s_waitcnt lgkmcnt(0)" ::: "memory");
    bf16x8 pf0 = *(const bf16x8*)&Plds[wave][lrow * LDP + quad * 8];
    bf16x8 pf1 = *(const bf16x8*)&Plds[wave][lrow * LDP + 32 + quad * 8];
    // ---- O += P V : vector B-operand loads from V^T ----
#pragma unroll
    for (int dt = 0; dt < 4; ++dt) {
      bf16x8 vf;
      vf = *(const bf16x8*)&Vth[(size_t)(dt * 16 + lrow) * SEQ + kbase + quad * 8];
      o_acc[dt] = __builtin_amdgcn_mfma_f32_16x16x32_bf16(pf0, vf, o_acc[dt], 0, 0, 0);
      vf = *(const bf16x8*)&Vth[(size_t)(dt * 16 + lrow) * SEQ + kbase + 32 + quad * 8];
      o_acc[dt] = __builtin_amdgcn_mfma_f32_16x16x32_bf16(pf1, vf, o_acc[dt], 0, 0, 0);
    }
  }
  // ---- epilogue ----
  bf16* Oh = O + (size_t)(b * SEQ) * DIMM + h * HD;
#pragma unroll
  for (int dt = 0; dt < 4; ++dt)
#pragma unroll
    for (int r = 0; r < 4; ++r) {
      const float val = o_acc[dt][r] / l_i[r];
      Oh[(size_t)(qbase + quad * 4 + r) * DIMM + dt * 16 + lrow] = (bf16)val;
    }
}

// ---------------- launch ----------------
extern "C" void kernel_launch(void* const* d_in, const int* in_sizes, int n_in,
                              void* d_out, int out_size, void* d_ws, size_t ws_size,
                              hipStream_t stream) {
  const float* x  = (const float*)d_in[0];
  const float* wq = (const float*)d_in[1];
  const float* wk = (const float*)d_in[2];
  const float* wv = (const float*)d_in[3];
  const float* wo = (const float*)d_in[4];

  bf16* Q   = (bf16*)d_ws;
  bf16* K   = Q  + (size_t)MTOT * DIMM;
  bf16* V   = K  + (size_t)MTOT * DIMM;
  bf16* Vt  = V  + (size_t)MTOT * DIMM;
  bf16* CTX = Vt + (size_t)MTOT * DIMM;
  float* out = (float*)d_out;

  dim3 blk(256);
  qkv_gemm<<<dim3(DIMM / 64, MTOT / 64, 3), blk, 0, stream>>>(x, wq, wk, wv, Q, K, V);
  vtrans<<<dim3(BATCH * NH * (SEQ / 64)), blk, 0, stream>>>(V, Vt);
  attn<<<dim3(BATCH * NH * (SEQ / 64)), blk, 0, stream>>>(Q, K, Vt, CTX);
  proj_gemm<<<dim3(DIMM / 64, MTOT / 64), blk, 0, stream>>>(CTX, wo, out);
}

// Round 4
// 330.990 us; speedup vs baseline: 1.4038x; 1.4038x over previous
//
#include <hip/hip_runtime.h>
#include <type_traits>

#define DIN 1024
#define DIMM 1024
#define NH 16
#define HD 64
#define SEQ 2048
#define BATCH 2
#define MTOT (BATCH*SEQ)   // 4096
#define LDT 40             // GEMM LDS leading dim (32 + 8 pad)
#define LDP 72             // attn P-tile leading dim (64 + 8): 16B-aligned rows
#define LDV 66             // transpose LDS leading dim
#define SCALE 0.125f       // 1/sqrt(64)

typedef __bf16 bf16;
typedef __bf16 bf16x8 __attribute__((ext_vector_type(8)));
typedef __bf16 bf16x4 __attribute__((ext_vector_type(4)));
typedef float f32x4 __attribute__((ext_vector_type(4)));

// Load 8 contiguous elements as bf16x8, converting from fp32 if needed.
template<typename T>
__device__ __forceinline__ bf16x8 ld8bf16(const T* __restrict__ p) {
  if constexpr (std::is_same<T, float>::value) {
    const f32x4* q = (const f32x4*)p;
    f32x4 a = q[0], b = q[1];
    bf16x8 r;
    r[0] = (bf16)a[0]; r[1] = (bf16)a[1]; r[2] = (bf16)a[2]; r[3] = (bf16)a[3];
    r[4] = (bf16)b[0]; r[5] = (bf16)b[1]; r[6] = (bf16)b[2]; r[7] = (bf16)b[3];
    return r;
  } else {
    return *(const bf16x8*)p;
  }
}

// ---------------- GEMM: C = A * W^T ---------------- (unchanged this round)
template<typename TA, typename TW, typename TC>
__device__ __forceinline__ void gemm_bt_body(const TA* __restrict__ A,
                                             const TW* __restrict__ W,
                                             TC* __restrict__ C,
                                             int M, int N, int K) {
  __shared__ bf16 As[64 * LDT];
  __shared__ bf16 Ws[64 * LDT];
  const int tid  = threadIdx.x;
  const int wave = tid >> 6;
  const int lane = tid & 63;
  const int mbase = blockIdx.y * 64;
  const int nbase = blockIdx.x * 64;
  const int lr = tid >> 2;
  const int lc = (tid & 3) * 8;
  const int frow = lane & 15;
  const int quad = lane >> 4;
  const int fk   = quad * 8;

  f32x4 acc[4] = {};

  for (int k0 = 0; k0 < K; k0 += 32) {
    *(bf16x8*)&As[lr * LDT + lc] = ld8bf16(&A[(size_t)(mbase + lr) * K + k0 + lc]);
    *(bf16x8*)&Ws[lr * LDT + lc] = ld8bf16(&W[(size_t)(nbase + lr) * K + k0 + lc]);
    __syncthreads();
    bf16x8 af = *(const bf16x8*)&As[(wave * 16 + frow) * LDT + fk];
#pragma unroll
    for (int nt = 0; nt < 4; ++nt) {
      bf16x8 bfr = *(const bf16x8*)&Ws[(nt * 16 + frow) * LDT + fk];
      acc[nt] = __builtin_amdgcn_mfma_f32_16x16x32_bf16(af, bfr, acc[nt], 0, 0, 0);
    }
    __syncthreads();
  }
  const int crow = mbase + wave * 16 + quad * 4;
  const int ccol = nbase + frow;
#pragma unroll
  for (int nt = 0; nt < 4; ++nt)
#pragma unroll
    for (int rr = 0; rr < 4; ++rr) {
      if constexpr (std::is_same<TC, float>::value)
        C[(size_t)(crow + rr) * N + ccol + nt * 16] = acc[nt][rr];
      else
        C[(size_t)(crow + rr) * N + ccol + nt * 16] = (bf16)acc[nt][rr];
    }
}

__global__ __launch_bounds__(256) void qkv_gemm(const float* __restrict__ x,
                                                const float* __restrict__ wq,
                                                const float* __restrict__ wk,
                                                const float* __restrict__ wv,
                                                bf16* __restrict__ q,
                                                bf16* __restrict__ k,
                                                bf16* __restrict__ v) {
  const float* W = (blockIdx.z == 0) ? wq : (blockIdx.z == 1) ? wk : wv;
  bf16* C        = (blockIdx.z == 0) ? q  : (blockIdx.z == 1) ? k  : v;
  gemm_bt_body<float, float, bf16>(x, W, C, MTOT, DIMM, DIN);
}

__global__ __launch_bounds__(256) void proj_gemm(const bf16* __restrict__ A,
                                                 const float* __restrict__ W,
                                                 float* __restrict__ C) {
  gemm_bt_body<bf16, float, float>(A, W, C, MTOT, DIMM, DIMM);
}

// ---------------- V transpose: V (b*S+s, h*64+d) -> Vt ((b*16+h)*64+d, s) ---
__global__ __launch_bounds__(256) void vtrans(const bf16* __restrict__ V,
                                              bf16* __restrict__ Vt) {
  __shared__ bf16 T[64 * LDV];   // [s_local][d]
  const int bh = blockIdx.x >> 5;       // 0..31
  const int st = blockIdx.x & 31;       // s-tile 0..31
  const int b  = bh >> 4;
  const int h  = bh & 15;
  const int t  = threadIdx.x;
  const int sr = t >> 3;                // 0..31
  const int dc = (t & 7) * 8;           // 0..56

  const bf16* src = V + ((size_t)(b * SEQ + st * 64)) * DIMM + h * HD;
#pragma unroll
  for (int half = 0; half < 2; ++half) {
    const int row = sr + half * 32;
    *(bf16x8*)&T[row * LDV + dc] = *(const bf16x8*)&src[(size_t)row * DIMM + dc];
  }
  __syncthreads();
  bf16* dst = Vt + (size_t)bh * 64 * SEQ + st * 64;
#pragma unroll
  for (int half = 0; half < 2; ++half) {
    const int d = sr + half * 32;
    bf16x8 o;
#pragma unroll
    for (int j = 0; j < 8; ++j)
      o[j] = T[(dc + j) * LDV + d];
    *(bf16x8*)&dst[(size_t)d * SEQ + dc] = o;
  }
}

// ---------------- Causal flash attention, transposed-S formulation ----------
// S^T = K Q^T  (A = K rows, B = Q rows; C-layout: row=k-idx, col=q-idx)
// softmax over k = in-lane over 16 regs + 2 shfl (quads)
// O^T = Vt P^T (A = Vt rows [d][s], B = P^T via LDS; C: row=d, col=q)
__global__ __launch_bounds__(256) void attn(const bf16* __restrict__ Q,
                                            const bf16* __restrict__ K,
                                            const bf16* __restrict__ Vt,
                                            bf16* __restrict__ O) {
  __shared__ bf16 Plds[4][16 * LDP];  // per-wave [q][k] 16x64
  const int wave = threadIdx.x >> 6;
  const int lane = threadIdx.x & 63;
  const int lrow = lane & 15;
  const int quad = lane >> 4;
  const int bh = blockIdx.x & 31;        // same-bh blocks -> same XCD residue
  const int qc = 31 - (blockIdx.x >> 5); // heavy q-chunks dispatch first
  const int b  = bh >> 4;
  const int h  = bh & 15;
  const int qbase = qc * 64 + wave * 16;

  const bf16* Qh  = Q  + (size_t)(b * SEQ) * DIMM + h * HD;
  const bf16* Kh  = K  + (size_t)(b * SEQ) * DIMM + h * HD;
  const bf16* Vth = Vt + (size_t)bh * 64 * SEQ;
  bf16* Pw = Plds[wave];

  // Q B-fragments (n = q = lrow, k = d)
  bf16x8 qf0 = *(const bf16x8*)&Qh[(size_t)(qbase + lrow) * DIMM + quad * 8];
  bf16x8 qf1 = *(const bf16x8*)&Qh[(size_t)(qbase + lrow) * DIMM + 32 + quad * 8];

  float m_i = -1e30f, l_i = 0.f;
  f32x4 o_acc[4] = {};

  const int nfull = qc;  // block-uniform: full (unmasked) 64-k tiles
  for (int kt = 0; kt <= nfull; ++kt) {
    const int kbase = kt * 64;
    // ---- S^T = K Q^T : 4 row-groups of 16 k, contraction d=64 ----
    f32x4 s[4] = {};
#pragma unroll
    for (int g = 0; g < 4; ++g) {
      bf16x8 kf;
      kf = *(const bf16x8*)&Kh[(size_t)(kbase + g * 16 + lrow) * DIMM + quad * 8];
      s[g] = __builtin_amdgcn_mfma_f32_16x16x32_bf16(kf, qf0, s[g], 0, 0, 0);
      kf = *(const bf16x8*)&Kh[(size_t)(kbase + g * 16 + lrow) * DIMM + 32 + quad * 8];
      s[g] = __builtin_amdgcn_mfma_f32_16x16x32_bf16(kf, qf1, s[g], 0, 0, 0);
    }
    // ---- causal mask: only the boundary tile needs it ----
    if (kt == nfull) {
      const int qrow = qbase + lrow;          // col = q
#pragma unroll
      for (int g = 0; g < 4; ++g)
#pragma unroll
        for (int r = 0; r < 4; ++r)
          s[g][r] = (kbase + g * 16 + quad * 4 + r > qrow) ? -1e30f : s[g][r];
    }
    // ---- online softmax over k (rows): in-lane + 2 shfl ----
    float pm = s[0][0];
#pragma unroll
    for (int g = 0; g < 4; ++g)
#pragma unroll
      for (int r = 0; r < 4; ++r) pm = fmaxf(pm, s[g][r]);
    pm = fmaxf(pm, __shfl_xor(pm, 16));
    pm = fmaxf(pm, __shfl_xor(pm, 32));
    const float mn = fmaxf(m_i, pm);
    const float al = __expf((m_i - mn) * SCALE);
    float sum = 0.f;
#pragma unroll
    for (int g = 0; g < 4; ++g) {
      bf16x4 pk;
#pragma unroll
      for (int r = 0; r < 4; ++r) {
        const float p = __expf((s[g][r] - mn) * SCALE);
        sum += p;
        pk[r] = (bf16)p;
      }
      *(bf16x4*)&Pw[lrow * LDP + g * 16 + quad * 4] = pk;  // [q][k], b64 write
    }
    sum += __shfl_xor(sum, 16);
    sum += __shfl_xor(sum, 32);
    l_i = l_i * al + sum;
    m_i = mn;
    // ---- rescale O^T ----
#pragma unroll
    for (int dt = 0; dt < 4; ++dt)
#pragma unroll
      for (int r = 0; r < 4; ++r)
        o_acc[dt][r] *= al;
    // ---- O^T += Vt P^T ----
    asm volatile("s_waitcnt lgkmcnt(0)" ::: "memory");
    bf16x8 pf0 = *(const bf16x8*)&Pw[lrow * LDP + quad * 8];       // k 0..31
    bf16x8 pf1 = *(const bf16x8*)&Pw[lrow * LDP + 32 + quad * 8];  // k 32..63
#pragma unroll
    for (int dt = 0; dt < 4; ++dt) {
      bf16x8 vf;
      vf = *(const bf16x8*)&Vth[(size_t)(dt * 16 + lrow) * SEQ + kbase + quad * 8];
      o_acc[dt] = __builtin_amdgcn_mfma_f32_16x16x32_bf16(vf, pf0, o_acc[dt], 0, 0, 0);
      vf = *(const bf16x8*)&Vth[(size_t)(dt * 16 + lrow) * SEQ + kbase + 32 + quad * 8];
      o_acc[dt] = __builtin_amdgcn_mfma_f32_16x16x32_bf16(vf, pf1, o_acc[dt], 0, 0, 0);
    }
  }
  // ---- epilogue: O^T C-layout (row=d-local, col=q) -> ctx (b,s,h*64+d) ----
  const float rl = __builtin_amdgcn_rcpf(l_i);
  bf16* Ob = O + (size_t)(b * SEQ + qbase + lrow) * DIMM + h * HD;
#pragma unroll
  for (int dt = 0; dt < 4; ++dt) {
    bf16x4 ov;
#pragma unroll
    for (int r = 0; r < 4; ++r)
      ov[r] = (bf16)(o_acc[dt][r] * rl);
    *(bf16x4*)&Ob[dt * 16 + quad * 4] = ov;  // 8B store, 8B-aligned
  }
}

// ---------------- launch ----------------
extern "C" void kernel_launch(void* const* d_in, const int* in_sizes, int n_in,
                              void* d_out, int out_size, void* d_ws, size_t ws_size,
                              hipStream_t stream) {
  const float* x  = (const float*)d_in[0];
  const float* wq = (const float*)d_in[1];
  const float* wk = (const float*)d_in[2];
  const float* wv = (const float*)d_in[3];
  const float* wo = (const float*)d_in[4];

  bf16* Q   = (bf16*)d_ws;
  bf16* K   = Q  + (size_t)MTOT * DIMM;
  bf16* V   = K  + (size_t)MTOT * DIMM;
  bf16* Vt  = V  + (size_t)MTOT * DIMM;
  bf16* CTX = Vt + (size_t)MTOT * DIMM;
  float* out = (float*)d_out;

  dim3 blk(256);
  qkv_gemm<<<dim3(DIMM / 64, MTOT / 64, 3), blk, 0, stream>>>(x, wq, wk, wv, Q, K, V);
  vtrans<<<dim3(BATCH * NH * (SEQ / 64)), blk, 0, stream>>>(V, Vt);
  attn<<<dim3(BATCH * NH * (SEQ / 64)), blk, 0, stream>>>(Q, K, Vt, CTX);
  proj_gemm<<<dim3(DIMM / 64, MTOT / 64), blk, 0, stream>>>(CTX, wo, out);
}

// Round 5
// 293.714 us; speedup vs baseline: 1.5819x; 1.1269x over previous
//
#include <hip/hip_runtime.h>
#include <stdint.h>

#define DIN 1024
#define DIMM 1024
#define NH 16
#define HD 64
#define SEQ 2048
#define BATCH 2
#define MTOT (BATCH*SEQ)   // 4096
#define LDP 72             // attn P-tile leading dim (64 + 8)
#define SCALE 0.125f       // 1/sqrt(64)

typedef __bf16 bf16;
typedef __bf16 bf16x8 __attribute__((ext_vector_type(8)));
typedef __bf16 bf16x4 __attribute__((ext_vector_type(4)));
typedef float f32x4 __attribute__((ext_vector_type(4)));

// async global->LDS, 16B per lane (HW: wave-uniform LDS base + lane*16)
__device__ __forceinline__ void async16(bf16* lds, const bf16* g) {
  __builtin_amdgcn_global_load_lds(
      (const __attribute__((address_space(1))) void*)g,
      (__attribute__((address_space(3))) void*)lds, 16, 0, 0);
}

// ---------------- fp32 -> bf16 convert: x (4M) + wq|wk|wv|wo (4M) ----------
__global__ __launch_bounds__(256) void convert_all(const float* __restrict__ x,
                                                   const float* __restrict__ wq,
                                                   const float* __restrict__ wk,
                                                   const float* __restrict__ wv,
                                                   const float* __restrict__ wo,
                                                   bf16* __restrict__ xb,
                                                   bf16* __restrict__ Wb) {
  const int t = blockIdx.x * 256 + threadIdx.x;
#pragma unroll
  for (int i = 0; i < 4; ++i) {
    const int c = t + i * 262144;   // 8-elem chunk id, total 1048576
    const float* src;
    bf16* dst;
    if (c < 524288) {               // x: 4M elems
      src = x + (size_t)c * 8;
      dst = xb + (size_t)c * 8;
    } else {
      const int cw = c - 524288;
      const int w = cw >> 17;       // 131072 chunks per weight
      const int off = (cw & 131071) * 8;
      const float* wp = (w == 0) ? wq : (w == 1) ? wk : (w == 2) ? wv : wo;
      src = wp + off;
      dst = Wb + (size_t)w * 1048576 + off;
    }
    f32x4 a = *(const f32x4*)src;
    f32x4 b = *(const f32x4*)(src + 4);
    bf16x8 r;
    r[0] = (bf16)a[0]; r[1] = (bf16)a[1]; r[2] = (bf16)a[2]; r[3] = (bf16)a[3];
    r[4] = (bf16)b[0]; r[5] = (bf16)b[1]; r[6] = (bf16)b[2]; r[7] = (bf16)b[3];
    *(bf16x8*)dst = r;
  }
}

// ---------------- m97-style 128x128 GEMM core (C = A * B^T, bf16) ----------
// A: M x K row-major, B: N x K row-major. BK=64, global_load_lds staging,
// 4 waves in 2x2, each 64x64 (4x4 MFMA tiles), acc in fp32.
__device__ __forceinline__ void mm128_core(const bf16* __restrict__ A,
                                           const bf16* __restrict__ B,
                                           int K, int mbase, int nbase,
                                           bf16* As, bf16* Bs,
                                           f32x4 acc[4][4]) {
  const int tid  = threadIdx.x;
  const int lane = tid & 63;
  const int wave = tid >> 6;
  const int lrow = lane & 15;
  const int quad = lane >> 4;
  const int wr = (wave >> 1) * 64;
  const int wc = (wave & 1) * 64;
  const int srow = tid >> 3;        // staging row within 32-row group
  const int scol = (tid & 7) * 8;   // staging col (elems)

  for (int k0 = 0; k0 < K; k0 += 64) {
#pragma unroll
    for (int i = 0; i < 4; ++i) {
      async16(&As[(i * 32 + srow) * 64 + scol],
              &A[(size_t)(mbase + i * 32 + srow) * K + k0 + scol]);
      async16(&Bs[(i * 32 + srow) * 64 + scol],
              &B[(size_t)(nbase + i * 32 + srow) * K + k0 + scol]);
    }
    __syncthreads();
#pragma unroll
    for (int h = 0; h < 2; ++h) {
      bf16x8 af[4], bfr[4];
#pragma unroll
      for (int i = 0; i < 4; ++i) {
        af[i]  = *(const bf16x8*)&As[(wr + i * 16 + lrow) * 64 + h * 32 + quad * 8];
        bfr[i] = *(const bf16x8*)&Bs[(wc + i * 16 + lrow) * 64 + h * 32 + quad * 8];
      }
#pragma unroll
      for (int mt = 0; mt < 4; ++mt)
#pragma unroll
        for (int nt = 0; nt < 4; ++nt)
          acc[mt][nt] = __builtin_amdgcn_mfma_f32_16x16x32_bf16(af[mt], bfr[nt], acc[mt][nt], 0, 0, 0);
    }
    __syncthreads();
  }
}

// QKV fused: B = [wq;wk;wv] (3072 x 1024). n<1024 -> Q, <2048 -> K, else V
// written TRANSPOSED into Vt ((b*16+h)*64+d, s).
__global__ __launch_bounds__(256) void qkv_gemm(const bf16* __restrict__ A,
                                                const bf16* __restrict__ B,
                                                bf16* __restrict__ Q,
                                                bf16* __restrict__ Kb,
                                                bf16* __restrict__ Vt) {
  __shared__ bf16 As[128 * 64];
  __shared__ bf16 Bs[128 * 64];
  const int lane = threadIdx.x & 63;
  const int wave = threadIdx.x >> 6;
  const int lrow = lane & 15;
  const int quad = lane >> 4;
  const int wr = (wave >> 1) * 64;
  const int wc = (wave & 1) * 64;
  const int mbase = blockIdx.y * 128;
  const int nbase = blockIdx.x * 128;

  f32x4 acc[4][4] = {};
  mm128_core(A, B, DIN, mbase, nbase, As, Bs, acc);

#pragma unroll
  for (int mt = 0; mt < 4; ++mt) {
    const int m0 = mbase + wr + mt * 16 + quad * 4;
#pragma unroll
    for (int nt = 0; nt < 4; ++nt) {
      const int n16 = nbase + wc + nt * 16;   // 16-aligned; region uniform
      const int n = n16 + lrow;
      if (n16 < 1024) {
#pragma unroll
        for (int rr = 0; rr < 4; ++rr)
          Q[(size_t)(m0 + rr) * 1024 + n] = (bf16)acc[mt][nt][rr];
      } else if (n16 < 2048) {
#pragma unroll
        for (int rr = 0; rr < 4; ++rr)
          Kb[(size_t)(m0 + rr) * 1024 + (n - 1024)] = (bf16)acc[mt][nt][rr];
      } else {
        const int nn = n - 2048;
        const int row = ((m0 >> 11) * 16 + (nn >> 6)) * 64 + (nn & 63);
        bf16x4 ov;
#pragma unroll
        for (int rr = 0; rr < 4; ++rr) ov[rr] = (bf16)acc[mt][nt][rr];
        *(bf16x4*)&Vt[(size_t)row * SEQ + (m0 & 2047)] = ov;
      }
    }
  }
}

__global__ __launch_bounds__(256) void proj_gemm(const bf16* __restrict__ A,
                                                 const bf16* __restrict__ B,
                                                 float* __restrict__ C) {
  __shared__ bf16 As[128 * 64];
  __shared__ bf16 Bs[128 * 64];
  const int lane = threadIdx.x & 63;
  const int wave = threadIdx.x >> 6;
  const int lrow = lane & 15;
  const int quad = lane >> 4;
  const int wr = (wave >> 1) * 64;
  const int wc = (wave & 1) * 64;
  const int mbase = blockIdx.y * 128;
  const int nbase = blockIdx.x * 128;

  f32x4 acc[4][4] = {};
  mm128_core(A, B, DIMM, mbase, nbase, As, Bs, acc);

#pragma unroll
  for (int mt = 0; mt < 4; ++mt) {
    const int m0 = mbase + wr + mt * 16 + quad * 4;
#pragma unroll
    for (int nt = 0; nt < 4; ++nt) {
      const int n = nbase + wc + nt * 16 + lrow;
#pragma unroll
      for (int rr = 0; rr < 4; ++rr)
        C[(size_t)(m0 + rr) * 1024 + n] = acc[mt][nt][rr];
    }
  }
}

// ---------------- Causal flash attention, transposed-S (R4 core) -----------
__global__ __launch_bounds__(256) void attn(const bf16* __restrict__ Q,
                                            const bf16* __restrict__ K,
                                            const bf16* __restrict__ Vt,
                                            bf16* __restrict__ O) {
  __shared__ bf16 Plds[4][16 * LDP];
  const int wave = threadIdx.x >> 6;
  const int lane = threadIdx.x & 63;
  const int lrow = lane & 15;
  const int quad = lane >> 4;
  const int bh = blockIdx.x & 31;        // same-bh -> same XCD residue
  // balanced qc partition: each mod-8 class {g0,15-g0,16+g0,31-g0} sums 66
  const int g  = blockIdx.x >> 5;
  const int j  = g >> 3, g0 = g & 7;
  const int qc = (j == 0) ? g0 : (j == 1) ? 15 - g0 : (j == 2) ? 16 + g0 : 31 - g0;
  const int b  = bh >> 4;
  const int h  = bh & 15;
  const int qbase = qc * 64 + wave * 16;

  const bf16* Qh  = Q  + (size_t)(b * SEQ) * DIMM + h * HD;
  const bf16* Kh  = K  + (size_t)(b * SEQ) * DIMM + h * HD;
  const bf16* Vth = Vt + (size_t)bh * 64 * SEQ;
  bf16* Pw = Plds[wave];

  bf16x8 qf0 = *(const bf16x8*)&Qh[(size_t)(qbase + lrow) * DIMM + quad * 8];
  bf16x8 qf1 = *(const bf16x8*)&Qh[(size_t)(qbase + lrow) * DIMM + 32 + quad * 8];

  float m_i = -1e30f, l_i = 0.f;
  f32x4 o_acc[4] = {};

  const int nfull = qc;
  for (int kt = 0; kt <= nfull; ++kt) {
    const int kbase = kt * 64;
    f32x4 s[4] = {};
#pragma unroll
    for (int gg = 0; gg < 4; ++gg) {
      bf16x8 kf;
      kf = *(const bf16x8*)&Kh[(size_t)(kbase + gg * 16 + lrow) * DIMM + quad * 8];
      s[gg] = __builtin_amdgcn_mfma_f32_16x16x32_bf16(kf, qf0, s[gg], 0, 0, 0);
      kf = *(const bf16x8*)&Kh[(size_t)(kbase + gg * 16 + lrow) * DIMM + 32 + quad * 8];
      s[gg] = __builtin_amdgcn_mfma_f32_16x16x32_bf16(kf, qf1, s[gg], 0, 0, 0);
    }
    if (kt == nfull) {
      const int qrow = qbase + lrow;
#pragma unroll
      for (int gg = 0; gg < 4; ++gg)
#pragma unroll
        for (int r = 0; r < 4; ++r)
          s[gg][r] = (kbase + gg * 16 + quad * 4 + r > qrow) ? -1e30f : s[gg][r];
    }
    float pm = s[0][0];
#pragma unroll
    for (int gg = 0; gg < 4; ++gg)
#pragma unroll
      for (int r = 0; r < 4; ++r) pm = fmaxf(pm, s[gg][r]);
    pm = fmaxf(pm, __shfl_xor(pm, 16));
    pm = fmaxf(pm, __shfl_xor(pm, 32));
    const float mn = fmaxf(m_i, pm);
    const float al = __expf((m_i - mn) * SCALE);
    float sum = 0.f;
#pragma unroll
    for (int gg = 0; gg < 4; ++gg) {
      bf16x4 pk;
#pragma unroll
      for (int r = 0; r < 4; ++r) {
        const float p = __expf((s[gg][r] - mn) * SCALE);
        sum += p;
        pk[r] = (bf16)p;
      }
      *(bf16x4*)&Pw[lrow * LDP + gg * 16 + quad * 4] = pk;
    }
    sum += __shfl_xor(sum, 16);
    sum += __shfl_xor(sum, 32);
    l_i = l_i * al + sum;
    m_i = mn;
#pragma unroll
    for (int dt = 0; dt < 4; ++dt)
#pragma unroll
      for (int r = 0; r < 4; ++r)
        o_acc[dt][r] *= al;
    asm volatile("s_waitcnt lgkmcnt(0)" ::: "memory");
    bf16x8 pf0 = *(const bf16x8*)&Pw[lrow * LDP + quad * 8];
    bf16x8 pf1 = *(const bf16x8*)&Pw[lrow * LDP + 32 + quad * 8];
#pragma unroll
    for (int dt = 0; dt < 4; ++dt) {
      bf16x8 vf;
      vf = *(const bf16x8*)&Vth[(size_t)(dt * 16 + lrow) * SEQ + kbase + quad * 8];
      o_acc[dt] = __builtin_amdgcn_mfma_f32_16x16x32_bf16(vf, pf0, o_acc[dt], 0, 0, 0);
      vf = *(const bf16x8*)&Vth[(size_t)(dt * 16 + lrow) * SEQ + kbase + 32 + quad * 8];
      o_acc[dt] = __builtin_amdgcn_mfma_f32_16x16x32_bf16(vf, pf1, o_acc[dt], 0, 0, 0);
    }
  }
  const float rl = __builtin_amdgcn_rcpf(l_i);
  bf16* Ob = O + (size_t)(b * SEQ + qbase + lrow) * DIMM + h * HD;
#pragma unroll
  for (int dt = 0; dt < 4; ++dt) {
    bf16x4 ov;
#pragma unroll
    for (int r = 0; r < 4; ++r)
      ov[r] = (bf16)(o_acc[dt][r] * rl);
    *(bf16x4*)&Ob[dt * 16 + quad * 4] = ov;
  }
}

// ---------------- launch ----------------
extern "C" void kernel_launch(void* const* d_in, const int* in_sizes, int n_in,
                              void* d_out, int out_size, void* d_ws, size_t ws_size,
                              hipStream_t stream) {
  const float* x  = (const float*)d_in[0];
  const float* wq = (const float*)d_in[1];
  const float* wk = (const float*)d_in[2];
  const float* wv = (const float*)d_in[3];
  const float* wo = (const float*)d_in[4];

  const size_t M4 = (size_t)MTOT * DIMM;  // 4M elems
  bf16* xb  = (bf16*)d_ws;                // 4M   (reused as CTX after qkv)
  bf16* Wb  = xb + M4;                    // 4M: [wq|wk|wv|wo]
  bf16* Q   = Wb + M4;                    // 4M
  bf16* Kb  = Q + M4;                     // 4M
  bf16* Vt  = Kb + M4;                    // 4M
  bf16* CTX = xb;                         // alias: xb dead after qkv_gemm
  float* out = (float*)d_out;

  dim3 blk(256);
  convert_all<<<dim3(1024), blk, 0, stream>>>(x, wq, wk, wv, wo, xb, Wb);
  qkv_gemm<<<dim3(3072 / 128, MTOT / 128), blk, 0, stream>>>(xb, Wb, Q, Kb, Vt);
  attn<<<dim3(BATCH * NH * (SEQ / 64)), blk, 0, stream>>>(Q, Kb, Vt, CTX);
  proj_gemm<<<dim3(1024 / 128, MTOT / 128), blk, 0, stream>>>(CTX, Wb + 3 * 1048576, out);
}

// Round 6
// 276.100 us; speedup vs baseline: 1.6828x; 1.0638x over previous
//
#include <hip/hip_runtime.h>
#include <stdint.h>

#define DIN 1024
#define DIMM 1024
#define NH 16
#define HD 64
#define SEQ 2048
#define BATCH 2
#define MTOT (BATCH*SEQ)   // 4096
#define LDP 72             // attn P-tile leading dim (64 + 8)
#define SCALE 0.125f       // 1/sqrt(64)

typedef __bf16 bf16;
typedef __bf16 bf16x8 __attribute__((ext_vector_type(8)));
typedef __bf16 bf16x4 __attribute__((ext_vector_type(4)));
typedef float f32x4 __attribute__((ext_vector_type(4)));

// async global->LDS, 16B per lane (HW: wave-uniform LDS base + lane*16)
__device__ __forceinline__ void async16(bf16* lds, const bf16* g) {
  __builtin_amdgcn_global_load_lds(
      (const __attribute__((address_space(1))) void*)g,
      (__attribute__((address_space(3))) void*)lds, 16, 0, 0);
}

// ---------------- fp32 -> bf16 convert: x (4M) + wq|wk|wv|wo (4M) ----------
__global__ __launch_bounds__(256) void convert_all(const float* __restrict__ x,
                                                   const float* __restrict__ wq,
                                                   const float* __restrict__ wk,
                                                   const float* __restrict__ wv,
                                                   const float* __restrict__ wo,
                                                   bf16* __restrict__ xb,
                                                   bf16* __restrict__ Wb) {
  const int t = blockIdx.x * 256 + threadIdx.x;
#pragma unroll
  for (int i = 0; i < 4; ++i) {
    const int c = t + i * 262144;   // 8-elem chunk id, total 1048576
    const float* src;
    bf16* dst;
    if (c < 524288) {               // x: 4M elems
      src = x + (size_t)c * 8;
      dst = xb + (size_t)c * 8;
    } else {
      const int cw = c - 524288;
      const int w = cw >> 17;       // 131072 chunks per weight
      const int off = (cw & 131071) * 8;
      const float* wp = (w == 0) ? wq : (w == 1) ? wk : (w == 2) ? wv : wo;
      src = wp + off;
      dst = Wb + (size_t)w * 1048576 + off;
    }
    f32x4 a = *(const f32x4*)src;
    f32x4 b = *(const f32x4*)(src + 4);
    bf16x8 r;
    r[0] = (bf16)a[0]; r[1] = (bf16)a[1]; r[2] = (bf16)a[2]; r[3] = (bf16)a[3];
    r[4] = (bf16)b[0]; r[5] = (bf16)b[1]; r[6] = (bf16)b[2]; r[7] = (bf16)b[3];
    *(bf16x8*)dst = r;
  }
}

// ---------------- m97-style 128x128 GEMM core (C = A * B^T, bf16) ----------
__device__ __forceinline__ void mm128_core(const bf16* __restrict__ A,
                                           const bf16* __restrict__ B,
                                           int K, int mbase, int nbase,
                                           bf16* As, bf16* Bs,
                                           f32x4 acc[4][4]) {
  const int tid  = threadIdx.x;
  const int lane = tid & 63;
  const int wave = tid >> 6;
  const int lrow = lane & 15;
  const int quad = lane >> 4;
  const int wr = (wave >> 1) * 64;
  const int wc = (wave & 1) * 64;
  const int srow = tid >> 3;        // staging row within 32-row group
  const int scol = (tid & 7) * 8;   // staging col (elems)

  for (int k0 = 0; k0 < K; k0 += 64) {
#pragma unroll
    for (int i = 0; i < 4; ++i) {
      async16(&As[(i * 32 + srow) * 64 + scol],
              &A[(size_t)(mbase + i * 32 + srow) * K + k0 + scol]);
      async16(&Bs[(i * 32 + srow) * 64 + scol],
              &B[(size_t)(nbase + i * 32 + srow) * K + k0 + scol]);
    }
    __syncthreads();
#pragma unroll
    for (int h = 0; h < 2; ++h) {
      bf16x8 af[4], bfr[4];
#pragma unroll
      for (int i = 0; i < 4; ++i) {
        af[i]  = *(const bf16x8*)&As[(wr + i * 16 + lrow) * 64 + h * 32 + quad * 8];
        bfr[i] = *(const bf16x8*)&Bs[(wc + i * 16 + lrow) * 64 + h * 32 + quad * 8];
      }
#pragma unroll
      for (int mt = 0; mt < 4; ++mt)
#pragma unroll
        for (int nt = 0; nt < 4; ++nt)
          acc[mt][nt] = __builtin_amdgcn_mfma_f32_16x16x32_bf16(af[mt], bfr[nt], acc[mt][nt], 0, 0, 0);
    }
    __syncthreads();
  }
}

// QKV fused: B = [wq;wk;wv] (3072 x 1024). n<1024 -> Q, <2048 -> K, else V
// written TRANSPOSED into Vt ((b*16+h)*64+d, s).
__global__ __launch_bounds__(256) void qkv_gemm(const bf16* __restrict__ A,
                                                const bf16* __restrict__ B,
                                                bf16* __restrict__ Q,
                                                bf16* __restrict__ Kb,
                                                bf16* __restrict__ Vt) {
  __shared__ bf16 As[128 * 64];
  __shared__ bf16 Bs[128 * 64];
  const int lane = threadIdx.x & 63;
  const int wave = threadIdx.x >> 6;
  const int lrow = lane & 15;
  const int quad = lane >> 4;
  const int wr = (wave >> 1) * 64;
  const int wc = (wave & 1) * 64;
  const int mbase = blockIdx.y * 128;
  const int nbase = blockIdx.x * 128;

  f32x4 acc[4][4] = {};
  mm128_core(A, B, DIN, mbase, nbase, As, Bs, acc);

#pragma unroll
  for (int mt = 0; mt < 4; ++mt) {
    const int m0 = mbase + wr + mt * 16 + quad * 4;
#pragma unroll
    for (int nt = 0; nt < 4; ++nt) {
      const int n16 = nbase + wc + nt * 16;   // 16-aligned; region uniform
      const int n = n16 + lrow;
      if (n16 < 1024) {
#pragma unroll
        for (int rr = 0; rr < 4; ++rr)
          Q[(size_t)(m0 + rr) * 1024 + n] = (bf16)acc[mt][nt][rr];
      } else if (n16 < 2048) {
#pragma unroll
        for (int rr = 0; rr < 4; ++rr)
          Kb[(size_t)(m0 + rr) * 1024 + (n - 1024)] = (bf16)acc[mt][nt][rr];
      } else {
        const int nn = n - 2048;
        const int row = ((m0 >> 11) * 16 + (nn >> 6)) * 64 + (nn & 63);
        bf16x4 ov;
#pragma unroll
        for (int rr = 0; rr < 4; ++rr) ov[rr] = (bf16)acc[mt][nt][rr];
        *(bf16x4*)&Vt[(size_t)row * SEQ + (m0 & 2047)] = ov;
      }
    }
  }
}

__global__ __launch_bounds__(256) void proj_gemm(const bf16* __restrict__ A,
                                                 const bf16* __restrict__ B,
                                                 float* __restrict__ C) {
  __shared__ bf16 As[128 * 64];
  __shared__ bf16 Bs[128 * 64];
  const int lane = threadIdx.x & 63;
  const int wave = threadIdx.x >> 6;
  const int lrow = lane & 15;
  const int quad = lane >> 4;
  const int wr = (wave >> 1) * 64;
  const int wc = (wave & 1) * 64;
  const int mbase = blockIdx.y * 128;
  const int nbase = blockIdx.x * 128;

  f32x4 acc[4][4] = {};
  mm128_core(A, B, DIMM, mbase, nbase, As, Bs, acc);

#pragma unroll
  for (int mt = 0; mt < 4; ++mt) {
    const int m0 = mbase + wr + mt * 16 + quad * 4;
#pragma unroll
    for (int nt = 0; nt < 4; ++nt) {
      const int n = nbase + wc + nt * 16 + lrow;
#pragma unroll
      for (int rr = 0; rr < 4; ++rr)
        C[(size_t)(m0 + rr) * 1024 + n] = acc[mt][nt][rr];
    }
  }
}

// ---------------- Causal flash attention, transposed-S, SW-pipelined -------
// S^T = K Q^T; softmax over k in-lane + 2 shfl; O^T = Vt P^T.
// Pipeline: K for tile kt+1 and Vt for tile kt are issued before the softmax
// so their latency hides behind VALU work. No manual waitcnt walls.
__global__ __launch_bounds__(256) void attn(const bf16* __restrict__ Q,
                                            const bf16* __restrict__ K,
                                            const bf16* __restrict__ Vt,
                                            bf16* __restrict__ O) {
  __shared__ bf16 Plds[4][16 * LDP];
  const int wave = threadIdx.x >> 6;
  const int lane = threadIdx.x & 63;
  const int lrow = lane & 15;
  const int quad = lane >> 4;
  const int bh = blockIdx.x & 31;        // same-bh -> same XCD residue
  const int g  = blockIdx.x >> 5;
  const int j  = g >> 3, g0 = g & 7;
  const int qc = (j == 0) ? g0 : (j == 1) ? 15 - g0 : (j == 2) ? 16 + g0 : 31 - g0;
  const int b  = bh >> 4;
  const int h  = bh & 15;
  const int qbase = qc * 64 + wave * 16;

  const bf16* Qh  = Q  + (size_t)(b * SEQ) * DIMM + h * HD;
  const bf16* Kh  = K  + (size_t)(b * SEQ) * DIMM + h * HD;
  const bf16* Vth = Vt + (size_t)bh * 64 * SEQ;
  bf16* Pw = Plds[wave];

  bf16x8 qf0 = *(const bf16x8*)&Qh[(size_t)(qbase + lrow) * DIMM + quad * 8];
  bf16x8 qf1 = *(const bf16x8*)&Qh[(size_t)(qbase + lrow) * DIMM + 32 + quad * 8];

  float m_i = -1e30f, l_i = 0.f;
  f32x4 o_acc[4] = {};
  const int nfull = qc;

  // K tile 0 prefetch
  bf16x8 kf[8];
#pragma unroll
  for (int gg = 0; gg < 4; ++gg) {
    kf[2 * gg]     = *(const bf16x8*)&Kh[(size_t)(gg * 16 + lrow) * DIMM + quad * 8];
    kf[2 * gg + 1] = *(const bf16x8*)&Kh[(size_t)(gg * 16 + lrow) * DIMM + 32 + quad * 8];
  }

  for (int kt = 0; kt <= nfull; ++kt) {
    const int kbase = kt * 64;
    // ---- S^T = K Q^T from prefetched kf ----
    f32x4 s[4] = {};
#pragma unroll
    for (int gg = 0; gg < 4; ++gg) {
      s[gg] = __builtin_amdgcn_mfma_f32_16x16x32_bf16(kf[2 * gg],     qf0, s[gg], 0, 0, 0);
      s[gg] = __builtin_amdgcn_mfma_f32_16x16x32_bf16(kf[2 * gg + 1], qf1, s[gg], 0, 0, 0);
    }
    // ---- issue Vt loads for this tile (independent of softmax) ----
    bf16x8 vf[8];
#pragma unroll
    for (int dt = 0; dt < 4; ++dt) {
      vf[2 * dt]     = *(const bf16x8*)&Vth[(size_t)(dt * 16 + lrow) * SEQ + kbase + quad * 8];
      vf[2 * dt + 1] = *(const bf16x8*)&Vth[(size_t)(dt * 16 + lrow) * SEQ + kbase + 32 + quad * 8];
    }
    // ---- prefetch next K tile (wave-uniform branch) ----
    if (kt < nfull) {
      const int nb = kbase + 64;
#pragma unroll
      for (int gg = 0; gg < 4; ++gg) {
        kf[2 * gg]     = *(const bf16x8*)&Kh[(size_t)(nb + gg * 16 + lrow) * DIMM + quad * 8];
        kf[2 * gg + 1] = *(const bf16x8*)&Kh[(size_t)(nb + gg * 16 + lrow) * DIMM + 32 + quad * 8];
      }
    }
    // ---- causal mask: boundary tile only ----
    if (kt == nfull) {
      const int qrow = qbase + lrow;
#pragma unroll
      for (int gg = 0; gg < 4; ++gg)
#pragma unroll
        for (int r = 0; r < 4; ++r)
          s[gg][r] = (kbase + gg * 16 + quad * 4 + r > qrow) ? -1e30f : s[gg][r];
    }
    // ---- online softmax over k: in-lane + 2 shfl ----
    float pm = s[0][0];
#pragma unroll
    for (int gg = 0; gg < 4; ++gg)
#pragma unroll
      for (int r = 0; r < 4; ++r) pm = fmaxf(pm, s[gg][r]);
    pm = fmaxf(pm, __shfl_xor(pm, 16));
    pm = fmaxf(pm, __shfl_xor(pm, 32));
    const float mn = fmaxf(m_i, pm);
    const float al = __expf((m_i - mn) * SCALE);
    float sum = 0.f;
#pragma unroll
    for (int gg = 0; gg < 4; ++gg) {
      bf16x4 pk;
#pragma unroll
      for (int r = 0; r < 4; ++r) {
        const float p = __expf((s[gg][r] - mn) * SCALE);
        sum += p;
        pk[r] = (bf16)p;
      }
      *(bf16x4*)&Pw[lrow * LDP + gg * 16 + quad * 4] = pk;
    }
    sum += __shfl_xor(sum, 16);
    sum += __shfl_xor(sum, 32);
    l_i = l_i * al + sum;
    m_i = mn;
#pragma unroll
    for (int dt = 0; dt < 4; ++dt)
#pragma unroll
      for (int r = 0; r < 4; ++r)
        o_acc[dt][r] *= al;
    // ---- P: C-layout -> B-operand via per-wave LDS (compiler-managed wait) --
    bf16x8 pf0 = *(const bf16x8*)&Pw[lrow * LDP + quad * 8];
    bf16x8 pf1 = *(const bf16x8*)&Pw[lrow * LDP + 32 + quad * 8];
    // ---- O^T += Vt P^T from prefetched vf ----
#pragma unroll
    for (int dt = 0; dt < 4; ++dt) {
      o_acc[dt] = __builtin_amdgcn_mfma_f32_16x16x32_bf16(vf[2 * dt],     pf0, o_acc[dt], 0, 0, 0);
      o_acc[dt] = __builtin_amdgcn_mfma_f32_16x16x32_bf16(vf[2 * dt + 1], pf1, o_acc[dt], 0, 0, 0);
    }
  }
  // ---- epilogue ----
  const float rl = __builtin_amdgcn_rcpf(l_i);
  bf16* Ob = O + (size_t)(b * SEQ + qbase + lrow) * DIMM + h * HD;
#pragma unroll
  for (int dt = 0; dt < 4; ++dt) {
    bf16x4 ov;
#pragma unroll
    for (int r = 0; r < 4; ++r)
      ov[r] = (bf16)(o_acc[dt][r] * rl);
    *(bf16x4*)&Ob[dt * 16 + quad * 4] = ov;
  }
}

// ---------------- launch ----------------
extern "C" void kernel_launch(void* const* d_in, const int* in_sizes, int n_in,
                              void* d_out, int out_size, void* d_ws, size_t ws_size,
                              hipStream_t stream) {
  const float* x  = (const float*)d_in[0];
  const float* wq = (const float*)d_in[1];
  const float* wk = (const float*)d_in[2];
  const float* wv = (const float*)d_in[3];
  const float* wo = (const float*)d_in[4];

  const size_t M4 = (size_t)MTOT * DIMM;  // 4M elems
  bf16* xb  = (bf16*)d_ws;                // 4M   (reused as CTX after qkv)
  bf16* Wb  = xb + M4;                    // 4M: [wq|wk|wv|wo]
  bf16* Q   = Wb + M4;                    // 4M
  bf16* Kb  = Q + M4;                     // 4M
  bf16* Vt  = Kb + M4;                    // 4M
  bf16* CTX = xb;                         // alias: xb dead after qkv_gemm
  float* out = (float*)d_out;

  dim3 blk(256);
  convert_all<<<dim3(1024), blk, 0, stream>>>(x, wq, wk, wv, wo, xb, Wb);
  qkv_gemm<<<dim3(3072 / 128, MTOT / 128), blk, 0, stream>>>(xb, Wb, Q, Kb, Vt);
  attn<<<dim3(BATCH * NH * (SEQ / 64)), blk, 0, stream>>>(Q, Kb, Vt, CTX);
  proj_gemm<<<dim3(1024 / 128, MTOT / 128), blk, 0, stream>>>(CTX, Wb + 3 * 1048576, out);
}